// Round 10
// baseline (4639.409 us; speedup 1.0000x reference)
//
#include <hip/hip_runtime.h>
#include <math.h>

#define LNUM 12
#define HNUM 12
#define EMB 768
#define TSEQ 1024
#define BBATCH 8
#define VOCAB 50257
#define NTOK (BBATCH*TSEQ)   // 8192

typedef unsigned short u16;
typedef __bf16 bf16_8 __attribute__((ext_vector_type(8)));
typedef float f32x4 __attribute__((ext_vector_type(4)));

__device__ __forceinline__ u16 f2bf(float f){
  unsigned u = __float_as_uint(f);
  u += 0x7fffu + ((u >> 16) & 1u);
  return (u16)(u >> 16);
}
__device__ __forceinline__ float wred(float v){
  #pragma unroll
  for (int m = 32; m; m >>= 1) v += __shfl_xor(v, m, 64);
  return v;
}

#define GLOAD_LDS16(g, l) \
  __builtin_amdgcn_global_load_lds((const __attribute__((address_space(1))) void*)(g), \
                                   (__attribute__((address_space(3))) void*)(l), 16, 0, 0)

template<int N> struct WCst { static constexpr int val = N; };

// ---------------- weight convert + transpose: src f32 [L][K][N] -> dst bf16 [L][N][K]
__global__ __launch_bounds__(256) void tcvt_kernel(const float* __restrict__ src,
                                                   u16* __restrict__ dst, int K, int N){
  __shared__ float tile[32][33];
  size_t off = (size_t)blockIdx.z * K * N;
  const float* s = src + off;
  u16* d = dst + off;
  int n0 = blockIdx.x * 32, k0 = blockIdx.y * 32;
  int tx = threadIdx.x & 31, ty = threadIdx.x >> 5;
  #pragma unroll
  for (int i = 0; i < 4; i++)
    tile[ty + i*8][tx] = s[(size_t)(k0 + ty + i*8) * N + n0 + tx];
  __syncthreads();
  #pragma unroll
  for (int i = 0; i < 4; i++){
    int n = ty + i*8;
    d[(size_t)(n0 + n) * K + k0 + tx] = f2bf(tile[tx][n]);
  }
}

// ---------------- embedding
__global__ __launch_bounds__(256) void embed_kernel(const int* __restrict__ x,
    const float* __restrict__ tok, const float* __restrict__ pos, float* __restrict__ h){
  int row = blockIdx.x;
  int t = row & (TSEQ - 1);
  int id = x[row];
  const float* te = tok + (size_t)id * EMB;
  const float* pe = pos + (size_t)t * EMB;
  float* hr = h + (size_t)row * EMB;
  for (int i = threadIdx.x; i < EMB; i += 256) hr[i] = te[i] + pe[i];
}

// ---------------- plain layernorm (row-per-block), bf16 out
__global__ __launch_bounds__(256) void ln_kernel(const float* __restrict__ x,
    const float* __restrict__ g, const float* __restrict__ b, u16* __restrict__ out){
  int row = blockIdx.x;
  const float* xr = x + (size_t)row * EMB;
  int tid = threadIdx.x, wave = tid >> 6, lane = tid & 63;
  float v[3]; float s = 0.f;
  #pragma unroll
  for (int i = 0; i < 3; i++){ v[i] = xr[tid + i*256]; s += v[i]; }
  __shared__ float red[4];
  s = wred(s);
  if (lane == 0) red[wave] = s;
  __syncthreads();
  float mu = (red[0] + red[1] + red[2] + red[3]) * (1.f / EMB);
  float ss = 0.f;
  #pragma unroll
  for (int i = 0; i < 3; i++){ float d = v[i] - mu; ss += d * d; }
  __syncthreads();
  ss = wred(ss);
  if (lane == 0) red[wave] = ss;
  __syncthreads();
  float var = (red[0] + red[1] + red[2] + red[3]) * (1.f / EMB);
  float rs = rsqrtf(var + 1e-5f);
  #pragma unroll
  for (int i = 0; i < 3; i++){
    int e = tid + i*256;
    out[(size_t)row * EMB + e] = f2bf(g[e] * (v[i] - mu) * rs + b[e]);
  }
}

// ---------------- merge (h += p0+p1+pbias) + layernorm.
// LASTF=0: grid NTOK, writes h (f32) and LN out (bf16).
// LASTF=1: grid BBATCH, row = last token; writes LN out f32 (lastb), h not written.
template<int LASTF>
__global__ __launch_bounds__(256) void ln_merge(const float* __restrict__ x,
    const float* __restrict__ p0, const float* __restrict__ p1,
    const float* __restrict__ pbias, const float* __restrict__ g,
    const float* __restrict__ b, float* __restrict__ hout, void* __restrict__ lnout){
  int orow = blockIdx.x;
  int row = LASTF ? (orow * TSEQ + (TSEQ - 1)) : orow;
  int tid = threadIdx.x, wave = tid >> 6, lane = tid & 63;
  float v[3]; float s = 0.f;
  #pragma unroll
  for (int i = 0; i < 3; i++){
    int e = tid + i*256;
    size_t idx = (size_t)row * EMB + e;
    v[i] = x[idx] + p0[idx] + p1[idx] + pbias[e];
    if (!LASTF) hout[idx] = v[i];
    s += v[i];
  }
  __shared__ float red[4];
  s = wred(s);
  if (lane == 0) red[wave] = s;
  __syncthreads();
  float mu = (red[0] + red[1] + red[2] + red[3]) * (1.f / EMB);
  float ss = 0.f;
  #pragma unroll
  for (int i = 0; i < 3; i++){ float d = v[i] - mu; ss += d * d; }
  __syncthreads();
  ss = wred(ss);
  if (lane == 0) red[wave] = ss;
  __syncthreads();
  float var = (red[0] + red[1] + red[2] + red[3]) * (1.f / EMB);
  float rs = rsqrtf(var + 1e-5f);
  #pragma unroll
  for (int i = 0; i < 3; i++){
    int e = tid + i*256;
    float o = g[e] * (v[i] - mu) * rs + b[e];
    if (LASTF) ((float*)lnout)[(size_t)orow * EMB + e] = o;
    else       ((u16*)lnout)[(size_t)orow * EMB + e] = f2bf(o);
  }
}

// ---------------- bf16 MFMA GEMM, wave tile 128x64, BK=32, BM=128, BN=NW*64.
// 3-slot LDS ring, stage t+2, counted vmcnt, raw s_barrier. Fragment-order LDS
// (conflict-free). KS-way split-K.
// XCD swizzle, bm FASTEST within each XCD chunk: the bn weight panel (BN x K bf16,
// 192-384KB) stays L2-resident across the ~64 bm blocks on that XCD -> B re-reads
// served by L2 instead of streaming 64x from L3 (the R5-R9 ~6 TB/s wall).
// EPI 0: f32 partial (no bias) -> out0/out1 by ks ; EPI 2: bf16 bias+gelu ;
// EPI 3: bf16 bias, cols<768 *0.125 (QKV).
template<int NW, int EPI, int KS>
__global__ __launch_bounds__(NW*64, 2) void gemm_wt(const u16* __restrict__ A,
    const u16* __restrict__ Bt, const float* __restrict__ bias,
    void* __restrict__ out0, void* __restrict__ out1, int K, int N){
  constexpr int BN    = NW * 64;
  constexpr int BGR   = BN / 16;         // B 1KB groups
  constexpr int NA    = 8 / NW;          // A stage instrs per wave
  constexpr int LOADS = NA + 4;          // stage instrs per wave per tile
  constexpr int SLOTE = (8 + BGR) * 512; // u16 per ring slot
  __shared__ __align__(16) u16 lds[3 * SLOTE];
  const int tid  = threadIdx.x;
  const int wave = tid >> 6, lane = tid & 63;
  const int q15  = lane & 15, ko = lane >> 4;
  // XCD-chunk swizzle (bijective: nwg % 8 == 0); bm fastest inside a chunk
  const int nwg = (int)gridDim.x, cpx = nwg >> 3, dd = (int)blockIdx.x;
  const int orig = (dd & 7) * cpx + (dd >> 3);
  constexpr int NBM = NTOK / 128;        // 64
  const int bm = orig % NBM;
  const int rest = orig / NBM;
  const int ks = (KS > 1) ? (rest % KS) : 0;
  const int bn = (KS > 1) ? (rest / KS) : rest;
  const int K2 = K / KS;
  const int NT = K2 >> 5;

  const u16* gA0 = A  + (size_t)(bm*128 + wave*NA*16 + q15) * K + (size_t)ks*K2 + ko*8;
  const u16* gB0 = Bt + (size_t)(bn*BN  + wave*4*16  + q15) * K + (size_t)ks*K2 + ko*8;

#define STAGE(tt) do { \
    int _t = (tt); \
    u16* _sl = lds + (_t % 3) * SLOTE; \
    _Pragma("unroll") \
    for (int _i = 0; _i < NA; _i++) \
      GLOAD_LDS16(gA0 + (size_t)_i*16*K + _t*32, _sl + (wave*NA + _i) * 512); \
    _Pragma("unroll") \
    for (int _i = 0; _i < 4; _i++) \
      GLOAD_LDS16(gB0 + (size_t)_i*16*K + _t*32, _sl + (8 + wave*4 + _i) * 512); \
  } while (0)

  f32x4 acc[8][4];
  #pragma unroll
  for (int i = 0; i < 8; i++)
    #pragma unroll
    for (int j = 0; j < 4; j++){ f32x4 z = {0.f,0.f,0.f,0.f}; acc[i][j] = z; }

  auto tile = [&](int t, auto wc, bool dostage, bool dosync){
    const u16* sl = lds + (t % 3) * SLOTE;
    bf16_8 af[8], bf[4];
    #pragma unroll
    for (int mi = 0; mi < 8; mi++)
      af[mi] = *(const bf16_8*)(sl + mi * 512 + lane * 8);           // broadcast
    #pragma unroll
    for (int ni = 0; ni < 4; ni++)
      bf[ni] = *(const bf16_8*)(sl + (8 + wave*4 + ni) * 512 + lane * 8);
    if (dostage) STAGE(t + 2);
    asm volatile("s_waitcnt lgkmcnt(0)" ::: "memory");
    __builtin_amdgcn_sched_barrier(0);
    __builtin_amdgcn_s_setprio(1);
    #pragma unroll
    for (int mi = 0; mi < 8; mi++)
      #pragma unroll
      for (int ni = 0; ni < 4; ni++)
        acc[mi][ni] = __builtin_amdgcn_mfma_f32_16x16x32_bf16(af[mi], bf[ni], acc[mi][ni], 0, 0, 0);
    __builtin_amdgcn_s_setprio(0);
    if (dosync){
      asm volatile("s_waitcnt vmcnt(%0)" :: "n"(decltype(wc)::val) : "memory");
      __builtin_amdgcn_sched_barrier(0);
      __builtin_amdgcn_s_barrier();
      __builtin_amdgcn_sched_barrier(0);
    }
  };

  // prologue: 2 batches in flight, confirm tile 0
  STAGE(0);
  STAGE(1);
  asm volatile("s_waitcnt vmcnt(%0)" :: "n"(LOADS) : "memory");
  __builtin_amdgcn_sched_barrier(0);
  __builtin_amdgcn_s_barrier();
  __builtin_amdgcn_sched_barrier(0);

  for (int t = 0; t < NT - 2; ++t) tile(t, WCst<LOADS>{}, true, true);
  tile(NT - 2, WCst<0>{}, false, true);
  tile(NT - 1, WCst<0>{}, false, false);
#undef STAGE

  const int colb = bn*BN + wave*64;
  const int rowb = bm*128;
  #pragma unroll
  for (int ni = 0; ni < 4; ni++){
    int col = colb + ni*16 + q15;
    float bv = (EPI == 0) ? 0.f : bias[col];
    #pragma unroll
    for (int mi = 0; mi < 8; mi++){
      #pragma unroll
      for (int j = 0; j < 4; j++){
        int row = rowb + mi*16 + ko*4 + j;
        float v = acc[mi][ni][j] + bv;
        if (EPI == 0){
          float* o = ks ? (float*)out1 : (float*)out0;
          o[(size_t)row * N + col] = v;
        } else if (EPI == 2){
          float y = 0.7978845608028654f * (v + 0.044715f * v * v * v);
          float e = __expf(fminf(2.f * y, 80.f));
          v = v * e / (e + 1.f);
          ((u16*)out0)[(size_t)row * N + col] = f2bf(v);
        } else {  // EPI == 3
          if (col < 768) v *= 0.125f;
          ((u16*)out0)[(size_t)row * N + col] = f2bf(v);
        }
      }
    }
  }
}

// ---------------- V transpose: qkvb bf16 [B*T][2304] (V = cols 1536+) -> vt [bh][64 d][1024 t]
__global__ __launch_bounds__(256) void vtrans_kernel(const u16* __restrict__ qkvb,
                                                     u16* __restrict__ vt){
  int wave = threadIdx.x >> 6, lane = threadIdx.x & 63;
  int bh = blockIdx.y, b = bh / HNUM, h = bh - b * HNUM;
  int t0 = blockIdx.x * 16 + wave * 4;
  const u16* src = qkvb + (size_t)b * TSEQ * 2304 + 1536 + h * 64 + lane;
  unsigned long long w = 0;
  #pragma unroll
  for (int i = 0; i < 4; i++)
    w |= (unsigned long long)src[(size_t)(t0 + i) * 2304] << (16 * i);
  *(unsigned long long*)(vt + ((size_t)bh * 64 + lane) * TSEQ + t0) = w;
}

// ---------------- MFMA flash attention. 4 independent waves/block, 64 q-rows each.
__global__ __launch_bounds__(256, 2) void attn_mfma(const u16* __restrict__ qkvb,
                                                    const u16* __restrict__ vt,
                                                    u16* __restrict__ ctx){
  __shared__ u16 plds[4][64][40];
  const int wave = threadIdx.x >> 6, lane = threadIdx.x & 63;
  const int g = lane >> 4, q15 = lane & 15;
  const int bh = blockIdx.y, b = bh / HNUM, h = bh - b * HNUM;
  const int q0 = ((int)gridDim.x - 1 - (int)blockIdx.x) * 256 + wave * 64;
  const u16* qk  = qkvb + (size_t)b * TSEQ * 2304 + h * 64;
  const u16* vtb = vt + (size_t)bh * 64 * TSEQ;

#define LOADKV(kb_, kd, vd) do { \
    _Pragma("unroll") \
    for (int _kf = 0; _kf < 2; _kf++) \
      _Pragma("unroll") \
      for (int _kc = 0; _kc < 2; _kc++) \
        kd[_kf][_kc] = *(const bf16_8*)(qk + (size_t)((kb_) + _kf*16 + q15) * 2304 + 768 + _kc*32 + g*8); \
    _Pragma("unroll") \
    for (int _dc = 0; _dc < 4; _dc++) \
      vd[_dc] = *(const bf16_8*)(vtb + (size_t)(_dc*16 + q15) * TSEQ + (kb_) + g*8); \
  } while (0)

  bf16_8 qfr[4][2];
  #pragma unroll
  for (int qf = 0; qf < 4; qf++)
    #pragma unroll
    for (int kc = 0; kc < 2; kc++)
      qfr[qf][kc] = *(const bf16_8*)(qk + (size_t)(q0 + qf*16 + q15) * 2304 + kc*32 + g*8);

  f32x4 oacc[4][4];
  #pragma unroll
  for (int i = 0; i < 4; i++)
    #pragma unroll
    for (int j = 0; j < 4; j++){ f32x4 z = {0.f,0.f,0.f,0.f}; oacc[i][j] = z; }
  float mx[4] = {-1e30f,-1e30f,-1e30f,-1e30f}, lsum[4] = {0.f,0.f,0.f,0.f};

  const int kbmax = q0 + 32;
  bf16_8 kcur[2][2], vcur[4];
  LOADKV(0, kcur, vcur);

  for (int kb = 0; kb <= kbmax; kb += 32){
    bf16_8 knxt[2][2], vnxt[4];
    if (kb < kbmax) LOADKV(kb + 32, knxt, vnxt);

    f32x4 s[2][4];
    #pragma unroll
    for (int kf = 0; kf < 2; kf++)
      #pragma unroll
      for (int qf = 0; qf < 4; qf++){
        f32x4 z = {0.f,0.f,0.f,0.f};
        z = __builtin_amdgcn_mfma_f32_16x16x32_bf16(kcur[kf][0], qfr[qf][0], z, 0, 0, 0);
        z = __builtin_amdgcn_mfma_f32_16x16x32_bf16(kcur[kf][1], qfr[qf][1], z, 0, 0, 0);
        s[kf][qf] = z;
      }

    if (kb + 31 > q0){
      #pragma unroll
      for (int kf = 0; kf < 2; kf++)
        #pragma unroll
        for (int qf = 0; qf < 4; qf++)
          #pragma unroll
          for (int j = 0; j < 4; j++)
            if (kb + kf*16 + g*4 + j > q0 + qf*16 + q15) s[kf][qf][j] = -1e30f;
    }

    #pragma unroll
    for (int qf = 0; qf < 4; qf++){
      float sm = -1e30f;
      #pragma unroll
      for (int kf = 0; kf < 2; kf++)
        #pragma unroll
        for (int j = 0; j < 4; j++) sm = fmaxf(sm, s[kf][qf][j]);
      sm = fmaxf(sm, __shfl_xor(sm, 16, 64));
      sm = fmaxf(sm, __shfl_xor(sm, 32, 64));
      float mn = fmaxf(mx[qf], sm);
      float c = __expf(mx[qf] - mn);
      mx[qf] = mn;
      float ps = 0.f;
      unsigned long long pw[2];
      #pragma unroll
      for (int kf = 0; kf < 2; kf++){
        unsigned long long w = 0;
        #pragma unroll
        for (int j = 0; j < 4; j++){
          float p = __expf(s[kf][qf][j] - mn);
          ps += p;
          w |= (unsigned long long)f2bf(p) << (16 * j);
        }
        pw[kf] = w;
      }
      ps += __shfl_xor(ps, 16, 64);
      ps += __shfl_xor(ps, 32, 64);
      lsum[qf] = lsum[qf] * c + ps;
      *(unsigned long long*)&plds[wave][qf*16 + q15][g*4]      = pw[0];
      *(unsigned long long*)&plds[wave][qf*16 + q15][16 + g*4] = pw[1];
      #pragma unroll
      for (int j = 0; j < 4; j++){
        float cr = __shfl(c, g*4 + j, 64);
        #pragma unroll
        for (int dc = 0; dc < 4; dc++) oacc[qf][dc][j] *= cr;
      }
    }

    asm volatile("s_waitcnt lgkmcnt(0)" ::: "memory");
    __builtin_amdgcn_sched_barrier(0);

    bf16_8 pa[4];
    #pragma unroll
    for (int qf = 0; qf < 4; qf++)
      pa[qf] = *(const bf16_8*)&plds[wave][qf*16 + q15][g*8];
    #pragma unroll
    for (int qf = 0; qf < 4; qf++)
      #pragma unroll
      for (int dc = 0; dc < 4; dc++)
        oacc[qf][dc] = __builtin_amdgcn_mfma_f32_16x16x32_bf16(pa[qf], vcur[dc], oacc[qf][dc], 0, 0, 0);

    if (kb < kbmax){
      #pragma unroll
      for (int kf = 0; kf < 2; kf++)
        #pragma unroll
        for (int kc = 0; kc < 2; kc++) kcur[kf][kc] = knxt[kf][kc];
      #pragma unroll
      for (int dc = 0; dc < 4; dc++) vcur[dc] = vnxt[dc];
    }
  }
#undef LOADKV

  u16* cb = ctx + ((size_t)(b * TSEQ + q0)) * EMB + h * 64;
  #pragma unroll
  for (int qf = 0; qf < 4; qf++){
    float inv = 1.f / lsum[qf];
    #pragma unroll
    for (int j = 0; j < 4; j++){
      float ir = __shfl(inv, g*4 + j, 64);
      int row = qf*16 + g*4 + j;
      #pragma unroll
      for (int dc = 0; dc < 4; dc++)
        cb[(size_t)row * EMB + dc*16 + q15] = f2bf(oacc[qf][dc][j] * ir);
    }
  }
}

// ---------------- final logits: out[b][v] = dot(last[b], tok[v]); one wave per v
__global__ __launch_bounds__(256) void logits_kernel(const float* __restrict__ last,
    const float* __restrict__ tok, float* __restrict__ out){
  __shared__ float ls[BBATCH * EMB];
  for (int i = threadIdx.x; i < BBATCH * EMB; i += 256) ls[i] = last[i];
  __syncthreads();
  int wave = threadIdx.x >> 6, lane = threadIdx.x & 63;
  int v = blockIdx.x * 4 + wave;
  if (v >= VOCAB) return;
  const float* tp = tok + (size_t)v * EMB;
  float acc[BBATCH];
  #pragma unroll
  for (int b = 0; b < BBATCH; b++) acc[b] = 0.f;
  #pragma unroll
  for (int i = 0; i < EMB/64; i++){
    float tv = tp[i*64 + lane];
    #pragma unroll
    for (int b = 0; b < BBATCH; b++) acc[b] += tv * ls[b*EMB + i*64 + lane];
  }
  #pragma unroll
  for (int b = 0; b < BBATCH; b++){
    float r = wred(acc[b]);
    if (lane == 0) out[(size_t)b * VOCAB + v] = r;
  }
}

extern "C" void kernel_launch(void* const* d_in, const int* in_sizes, int n_in,
                              void* d_out, int out_size, void* d_ws, size_t ws_size,
                              hipStream_t stream){
  const int*   x    = (const int*)  d_in[0];
  const float* tok  = (const float*)d_in[1];
  const float* pos  = (const float*)d_in[2];
  const float* ln1g = (const float*)d_in[3];
  const float* ln1b = (const float*)d_in[4];
  const float* Wqkv = (const float*)d_in[5];
  const float* bqkv = (const float*)d_in[6];
  const float* Wo   = (const float*)d_in[7];
  const float* bo   = (const float*)d_in[8];
  const float* ln2g = (const float*)d_in[9];
  const float* ln2b = (const float*)d_in[10];
  const float* W1   = (const float*)d_in[11];
  const float* b1   = (const float*)d_in[12];
  const float* W2   = (const float*)d_in[13];
  const float* b2   = (const float*)d_in[14];
  const float* lnfg = (const float*)d_in[15];
  const float* lnfb = (const float*)d_in[16];

  char* p = (char*)d_ws;
  u16* wqkvT = (u16*)p;  p += (size_t)LNUM*2304*768*2;
  u16* woT   = (u16*)p;  p += (size_t)LNUM*768*768*2;
  u16* w1T   = (u16*)p;  p += (size_t)LNUM*3072*768*2;
  u16* w2T   = (u16*)p;  p += (size_t)LNUM*768*3072*2;
  float* h   = (float*)p; p += (size_t)NTOK*EMB*4;
  u16* abuf  = (u16*)p;  p += (size_t)NTOK*EMB*2;      // ctx; also pf1 low half
  u16* vt    = (u16*)p;  p += (size_t)NTOK*EMB*2;      // V^T; also pf1 high half (contiguous with abuf)
  char* tmp  = p;        p += (size_t)NTOK*2304*4;     // 75.5MB overlay region
  float* lastb = (float*)p; p += (size_t)BBATCH*EMB*4;
  if (ws_size < (size_t)(p - (char*)d_ws)) return;

  const size_t SZ_A  = (size_t)NTOK*EMB*2;             // 12.6MB bf16 activations
  u16*   aln  = (u16*)tmp;                             // [0, 12.6)
  u16*   qkvb = (u16*)(tmp + SZ_A);                    // [12.6, 50.3)
  float* pp0  = (float*)(tmp + SZ_A);                  // proj partials [12.6, 62.9)
  float* pp1  = (float*)(tmp + SZ_A + (size_t)NTOK*EMB*4);
  u16*   a2   = (u16*)(tmp + SZ_A + 2*(size_t)NTOK*EMB*4);  // [62.9, 75.5)
  u16*   ff   = (u16*)tmp;                             // [0, 50.3)
  float* pf0  = (float*)(tmp + 4*SZ_A);                // [50.3, 75.5)
  float* pf1  = (float*)abuf;                          // abuf+vt contiguous [25.2MB]

  tcvt_kernel<<<dim3(2304/32, 768/32, LNUM), 256, 0, stream>>>(Wqkv, wqkvT, 768, 2304);
  tcvt_kernel<<<dim3(768/32,  768/32, LNUM), 256, 0, stream>>>(Wo,   woT,   768, 768);
  tcvt_kernel<<<dim3(3072/32, 768/32, LNUM), 256, 0, stream>>>(W1,   w1T,   768, 3072);
  tcvt_kernel<<<dim3(768/32, 3072/32, LNUM), 256, 0, stream>>>(W2,   w2T,   3072, 768);
  embed_kernel<<<NTOK, 256, 0, stream>>>(x, tok, pos, h);

  ln_kernel<<<NTOK, 256, 0, stream>>>(h, ln1g, ln1b, aln);
  for (int l = 0; l < LNUM; l++){
    // QKV: [8192,768]x[768,2304], BN=256 -> grid 64*9=576
    gemm_wt<4,3,1><<<(NTOK/128)*(2304/256), 256, 0, stream>>>(
        aln, wqkvT + (size_t)l*2304*768, bqkv + (size_t)l*2304, qkvb, nullptr, 768, 2304);
    vtrans_kernel<<<dim3(TSEQ/16, BBATCH*HNUM), 256, 0, stream>>>(qkvb, vt);
    attn_mfma<<<dim3(TSEQ/256, BBATCH*HNUM), 256, 0, stream>>>(qkvb, vt, abuf);
    // proj: split-K2, BN=128 -> grid 64*6*2=768 (f32 partials, no bias)
    gemm_wt<2,0,2><<<(NTOK/128)*(768/128)*2, 128, 0, stream>>>(
        abuf, woT + (size_t)l*768*768, nullptr, pp0, pp1, 768, 768);
    ln_merge<0><<<NTOK, 256, 0, stream>>>(h, pp0, pp1, bo + (size_t)l*768,
        ln2g + (size_t)l*EMB, ln2b + (size_t)l*EMB, h, a2);
    // FF1: BN=256 -> grid 64*12=768, gelu bf16
    gemm_wt<4,2,1><<<(NTOK/128)*(3072/256), 256, 0, stream>>>(
        a2, w1T + (size_t)l*3072*768, b1 + (size_t)l*3072, ff, nullptr, 768, 3072);
    // FF2: split-K2 (K=3072), BN=128 -> grid 768 (f32 partials)
    gemm_wt<2,0,2><<<(NTOK/128)*(768/128)*2, 128, 0, stream>>>(
        ff, w2T + (size_t)l*768*3072, nullptr, pf0, pf1, 3072, 768);
    if (l < LNUM - 1)
      ln_merge<0><<<NTOK, 256, 0, stream>>>(h, pf0, pf1, b2 + (size_t)l*768,
          ln1g + (size_t)(l+1)*EMB, ln1b + (size_t)(l+1)*EMB, h, aln);
  }
  ln_merge<1><<<BBATCH, 256, 0, stream>>>(h, pf0, pf1, b2 + (size_t)(LNUM-1)*768,
      lnfg, lnfb, nullptr, lastb);
  logits_kernel<<<(VOCAB + 3)/4, 256, 0, stream>>>(lastb, tok, (float*)d_out);
}

// Round 11
// 4340.306 us; speedup vs baseline: 1.0689x; 1.0689x over previous
//
#include <hip/hip_runtime.h>
#include <math.h>

#define LNUM 12
#define HNUM 12
#define EMB 768
#define TSEQ 1024
#define BBATCH 8
#define VOCAB 50257
#define NTOK (BBATCH*TSEQ)   // 8192

typedef unsigned short u16;
typedef __bf16 bf16_8 __attribute__((ext_vector_type(8)));
typedef float f32x4 __attribute__((ext_vector_type(4)));

__device__ __forceinline__ u16 f2bf(float f){
  unsigned u = __float_as_uint(f);
  u += 0x7fffu + ((u >> 16) & 1u);
  return (u16)(u >> 16);
}
__device__ __forceinline__ float wred(float v){
  #pragma unroll
  for (int m = 32; m; m >>= 1) v += __shfl_xor(v, m, 64);
  return v;
}

#define GLOAD_LDS16(g, l) \
  __builtin_amdgcn_global_load_lds((const __attribute__((address_space(1))) void*)(g), \
                                   (__attribute__((address_space(3))) void*)(l), 16, 0, 0)

template<int N> struct WCst { static constexpr int val = N; };

// ---------------- weight convert + transpose: src f32 [L][K][N] -> dst bf16 [L][N][K]
__global__ __launch_bounds__(256) void tcvt_kernel(const float* __restrict__ src,
                                                   u16* __restrict__ dst, int K, int N){
  __shared__ float tile[32][33];
  size_t off = (size_t)blockIdx.z * K * N;
  const float* s = src + off;
  u16* d = dst + off;
  int n0 = blockIdx.x * 32, k0 = blockIdx.y * 32;
  int tx = threadIdx.x & 31, ty = threadIdx.x >> 5;
  #pragma unroll
  for (int i = 0; i < 4; i++)
    tile[ty + i*8][tx] = s[(size_t)(k0 + ty + i*8) * N + n0 + tx];
  __syncthreads();
  #pragma unroll
  for (int i = 0; i < 4; i++){
    int n = ty + i*8;
    d[(size_t)(n0 + n) * K + k0 + tx] = f2bf(tile[tx][n]);
  }
}

// ---------------- embedding
__global__ __launch_bounds__(256) void embed_kernel(const int* __restrict__ x,
    const float* __restrict__ tok, const float* __restrict__ pos, float* __restrict__ h){
  int row = blockIdx.x;
  int t = row & (TSEQ - 1);
  int id = x[row];
  const float* te = tok + (size_t)id * EMB;
  const float* pe = pos + (size_t)t * EMB;
  float* hr = h + (size_t)row * EMB;
  for (int i = threadIdx.x; i < EMB; i += 256) hr[i] = te[i] + pe[i];
}

// ---------------- plain layernorm (row-per-block), bf16 out
__global__ __launch_bounds__(256) void ln_kernel(const float* __restrict__ x,
    const float* __restrict__ g, const float* __restrict__ b, u16* __restrict__ out){
  int row = blockIdx.x;
  const float* xr = x + (size_t)row * EMB;
  int tid = threadIdx.x, wave = tid >> 6, lane = tid & 63;
  float v[3]; float s = 0.f;
  #pragma unroll
  for (int i = 0; i < 3; i++){ v[i] = xr[tid + i*256]; s += v[i]; }
  __shared__ float red[4];
  s = wred(s);
  if (lane == 0) red[wave] = s;
  __syncthreads();
  float mu = (red[0] + red[1] + red[2] + red[3]) * (1.f / EMB);
  float ss = 0.f;
  #pragma unroll
  for (int i = 0; i < 3; i++){ float d = v[i] - mu; ss += d * d; }
  __syncthreads();
  ss = wred(ss);
  if (lane == 0) red[wave] = ss;
  __syncthreads();
  float var = (red[0] + red[1] + red[2] + red[3]) * (1.f / EMB);
  float rs = rsqrtf(var + 1e-5f);
  #pragma unroll
  for (int i = 0; i < 3; i++){
    int e = tid + i*256;
    out[(size_t)row * EMB + e] = f2bf(g[e] * (v[i] - mu) * rs + b[e]);
  }
}

// ---------------- merge (h += p0+p1+pbias) + layernorm.
// LASTF=0: grid NTOK, writes h (f32) and LN out (bf16).
// LASTF=1: grid BBATCH, row = last token; writes LN out f32 (lastb), h not written.
template<int LASTF>
__global__ __launch_bounds__(256) void ln_merge(const float* __restrict__ x,
    const float* __restrict__ p0, const float* __restrict__ p1,
    const float* __restrict__ pbias, const float* __restrict__ g,
    const float* __restrict__ b, float* __restrict__ hout, void* __restrict__ lnout){
  int orow = blockIdx.x;
  int row = LASTF ? (orow * TSEQ + (TSEQ - 1)) : orow;
  int tid = threadIdx.x, wave = tid >> 6, lane = tid & 63;
  float v[3]; float s = 0.f;
  #pragma unroll
  for (int i = 0; i < 3; i++){
    int e = tid + i*256;
    size_t idx = (size_t)row * EMB + e;
    v[i] = x[idx] + p0[idx] + p1[idx] + pbias[e];
    if (!LASTF) hout[idx] = v[i];
    s += v[i];
  }
  __shared__ float red[4];
  s = wred(s);
  if (lane == 0) red[wave] = s;
  __syncthreads();
  float mu = (red[0] + red[1] + red[2] + red[3]) * (1.f / EMB);
  float ss = 0.f;
  #pragma unroll
  for (int i = 0; i < 3; i++){ float d = v[i] - mu; ss += d * d; }
  __syncthreads();
  ss = wred(ss);
  if (lane == 0) red[wave] = ss;
  __syncthreads();
  float var = (red[0] + red[1] + red[2] + red[3]) * (1.f / EMB);
  float rs = rsqrtf(var + 1e-5f);
  #pragma unroll
  for (int i = 0; i < 3; i++){
    int e = tid + i*256;
    float o = g[e] * (v[i] - mu) * rs + b[e];
    if (LASTF) ((float*)lnout)[(size_t)orow * EMB + e] = o;
    else       ((u16*)lnout)[(size_t)orow * EMB + e] = f2bf(o);
  }
}

// ---------------- bf16 MFMA GEMM, wave tile 128x64, BK=32, BM=128, BN=NW*64.
// 3-slot LDS ring, stage t+2, counted vmcnt, raw s_barrier. Fragment-order LDS
// (conflict-free). KS-way split-K (ks folded as outer column index).
// GROUPED RASTERIZATION within the per-XCD chunk: consecutive orig ids fill an
// 8(bm) x GBN(col) group (bm fastest), groups advance bm-major -> the concurrent
// ~64 blocks/XCD touch only ~8 A panels (1.5MB) + ~GBN B panels (~1.2MB), both
// L2-resident (4MB/XCD). R9 (bn-fastest, B thrash, FETCH 52MB) and R10
// (bm-fastest, A thrash, FETCH 78MB) both measured ~100us; this fixes both.
// EPI 0: f32 partial (no bias) -> out0/out1 by ks ; EPI 2: bf16 bias+gelu ;
// EPI 3: bf16 bias, cols<768 *0.125 (QKV).
template<int NW, int EPI, int KS, int GBN>
__global__ __launch_bounds__(NW*64, 2) void gemm_wt(const u16* __restrict__ A,
    const u16* __restrict__ Bt, const float* __restrict__ bias,
    void* __restrict__ out0, void* __restrict__ out1, int K, int N){
  constexpr int BN    = NW * 64;
  constexpr int BGR   = BN / 16;         // B 1KB groups
  constexpr int NA    = 8 / NW;          // A stage instrs per wave
  constexpr int LOADS = NA + 4;          // stage instrs per wave per tile
  constexpr int SLOTE = (8 + BGR) * 512; // u16 per ring slot
  __shared__ __align__(16) u16 lds[3 * SLOTE];
  const int tid  = threadIdx.x;
  const int wave = tid >> 6, lane = tid & 63;
  const int q15  = lane & 15, ko = lane >> 4;
  // XCD-chunk swizzle (bijective: nwg % 8 == 0) -> orig sequential per XCD
  const int nwg = (int)gridDim.x, cpx = nwg >> 3, dd = (int)blockIdx.x;
  const int orig = (dd & 7) * cpx + (dd >> 3);
  // grouped rasterization: 8 bm x GBN col per group, bm fastest; gm fastest across groups
  constexpr int NBM = NTOK / 128;        // 64
  const int NBN = N / BN;
  const int g  = orig / (8 * GBN), r = orig % (8 * GBN);
  const int bm  = (g % (NBM / 8)) * 8 + (r & 7);
  const int cix = (g / (NBM / 8)) * GBN + (r >> 3);
  const int ks = (KS > 1) ? (cix / NBN) : 0;
  const int bn = (KS > 1) ? (cix % NBN) : cix;
  const int K2 = K / KS;
  const int NT = K2 >> 5;

  const u16* gA0 = A  + (size_t)(bm*128 + wave*NA*16 + q15) * K + (size_t)ks*K2 + ko*8;
  const u16* gB0 = Bt + (size_t)(bn*BN  + wave*4*16  + q15) * K + (size_t)ks*K2 + ko*8;

#define STAGE(tt) do { \
    int _t = (tt); \
    u16* _sl = lds + (_t % 3) * SLOTE; \
    _Pragma("unroll") \
    for (int _i = 0; _i < NA; _i++) \
      GLOAD_LDS16(gA0 + (size_t)_i*16*K + _t*32, _sl + (wave*NA + _i) * 512); \
    _Pragma("unroll") \
    for (int _i = 0; _i < 4; _i++) \
      GLOAD_LDS16(gB0 + (size_t)_i*16*K + _t*32, _sl + (8 + wave*4 + _i) * 512); \
  } while (0)

  f32x4 acc[8][4];
  #pragma unroll
  for (int i = 0; i < 8; i++)
    #pragma unroll
    for (int j = 0; j < 4; j++){ f32x4 z = {0.f,0.f,0.f,0.f}; acc[i][j] = z; }

  auto tile = [&](int t, auto wc, bool dostage, bool dosync){
    const u16* sl = lds + (t % 3) * SLOTE;
    bf16_8 af[8], bf[4];
    #pragma unroll
    for (int mi = 0; mi < 8; mi++)
      af[mi] = *(const bf16_8*)(sl + mi * 512 + lane * 8);           // broadcast
    #pragma unroll
    for (int ni = 0; ni < 4; ni++)
      bf[ni] = *(const bf16_8*)(sl + (8 + wave*4 + ni) * 512 + lane * 8);
    if (dostage) STAGE(t + 2);
    asm volatile("s_waitcnt lgkmcnt(0)" ::: "memory");
    __builtin_amdgcn_sched_barrier(0);
    __builtin_amdgcn_s_setprio(1);
    #pragma unroll
    for (int mi = 0; mi < 8; mi++)
      #pragma unroll
      for (int ni = 0; ni < 4; ni++)
        acc[mi][ni] = __builtin_amdgcn_mfma_f32_16x16x32_bf16(af[mi], bf[ni], acc[mi][ni], 0, 0, 0);
    __builtin_amdgcn_s_setprio(0);
    if (dosync){
      asm volatile("s_waitcnt vmcnt(%0)" :: "n"(decltype(wc)::val) : "memory");
      __builtin_amdgcn_sched_barrier(0);
      __builtin_amdgcn_s_barrier();
      __builtin_amdgcn_sched_barrier(0);
    }
  };

  // prologue: 2 batches in flight, confirm tile 0
  STAGE(0);
  STAGE(1);
  asm volatile("s_waitcnt vmcnt(%0)" :: "n"(LOADS) : "memory");
  __builtin_amdgcn_sched_barrier(0);
  __builtin_amdgcn_s_barrier();
  __builtin_amdgcn_sched_barrier(0);

  for (int t = 0; t < NT - 2; ++t) tile(t, WCst<LOADS>{}, true, true);
  tile(NT - 2, WCst<0>{}, false, true);
  tile(NT - 1, WCst<0>{}, false, false);
#undef STAGE

  const int colb = bn*BN + wave*64;
  const int rowb = bm*128;
  #pragma unroll
  for (int ni = 0; ni < 4; ni++){
    int col = colb + ni*16 + q15;
    float bv = (EPI == 0) ? 0.f : bias[col];
    #pragma unroll
    for (int mi = 0; mi < 8; mi++){
      #pragma unroll
      for (int j = 0; j < 4; j++){
        int row = rowb + mi*16 + ko*4 + j;
        float v = acc[mi][ni][j] + bv;
        if (EPI == 0){
          float* o = ks ? (float*)out1 : (float*)out0;
          o[(size_t)row * N + col] = v;
        } else if (EPI == 2){
          float y = 0.7978845608028654f * (v + 0.044715f * v * v * v);
          float e = __expf(fminf(2.f * y, 80.f));
          v = v * e / (e + 1.f);
          ((u16*)out0)[(size_t)row * N + col] = f2bf(v);
        } else {  // EPI == 3
          if (col < 768) v *= 0.125f;
          ((u16*)out0)[(size_t)row * N + col] = f2bf(v);
        }
      }
    }
  }
}

// ---------------- V transpose: qkvb bf16 [B*T][2304] (V = cols 1536+) -> vt [bh][64 d][1024 t]
__global__ __launch_bounds__(256) void vtrans_kernel(const u16* __restrict__ qkvb,
                                                     u16* __restrict__ vt){
  int wave = threadIdx.x >> 6, lane = threadIdx.x & 63;
  int bh = blockIdx.y, b = bh / HNUM, h = bh - b * HNUM;
  int t0 = blockIdx.x * 16 + wave * 4;
  const u16* src = qkvb + (size_t)b * TSEQ * 2304 + 1536 + h * 64 + lane;
  unsigned long long w = 0;
  #pragma unroll
  for (int i = 0; i < 4; i++)
    w |= (unsigned long long)src[(size_t)(t0 + i) * 2304] << (16 * i);
  *(unsigned long long*)(vt + ((size_t)bh * 64 + lane) * TSEQ + t0) = w;
}

// ---------------- MFMA flash attention. 4 independent waves/block, 64 q-rows each.
__global__ __launch_bounds__(256, 2) void attn_mfma(const u16* __restrict__ qkvb,
                                                    const u16* __restrict__ vt,
                                                    u16* __restrict__ ctx){
  __shared__ u16 plds[4][64][40];
  const int wave = threadIdx.x >> 6, lane = threadIdx.x & 63;
  const int g = lane >> 4, q15 = lane & 15;
  const int bh = blockIdx.y, b = bh / HNUM, h = bh - b * HNUM;
  const int q0 = ((int)gridDim.x - 1 - (int)blockIdx.x) * 256 + wave * 64;
  const u16* qk  = qkvb + (size_t)b * TSEQ * 2304 + h * 64;
  const u16* vtb = vt + (size_t)bh * 64 * TSEQ;

#define LOADKV(kb_, kd, vd) do { \
    _Pragma("unroll") \
    for (int _kf = 0; _kf < 2; _kf++) \
      _Pragma("unroll") \
      for (int _kc = 0; _kc < 2; _kc++) \
        kd[_kf][_kc] = *(const bf16_8*)(qk + (size_t)((kb_) + _kf*16 + q15) * 2304 + 768 + _kc*32 + g*8); \
    _Pragma("unroll") \
    for (int _dc = 0; _dc < 4; _dc++) \
      vd[_dc] = *(const bf16_8*)(vtb + (size_t)(_dc*16 + q15) * TSEQ + (kb_) + g*8); \
  } while (0)

  bf16_8 qfr[4][2];
  #pragma unroll
  for (int qf = 0; qf < 4; qf++)
    #pragma unroll
    for (int kc = 0; kc < 2; kc++)
      qfr[qf][kc] = *(const bf16_8*)(qk + (size_t)(q0 + qf*16 + q15) * 2304 + kc*32 + g*8);

  f32x4 oacc[4][4];
  #pragma unroll
  for (int i = 0; i < 4; i++)
    #pragma unroll
    for (int j = 0; j < 4; j++){ f32x4 z = {0.f,0.f,0.f,0.f}; oacc[i][j] = z; }
  float mx[4] = {-1e30f,-1e30f,-1e30f,-1e30f}, lsum[4] = {0.f,0.f,0.f,0.f};

  const int kbmax = q0 + 32;
  bf16_8 kcur[2][2], vcur[4];
  LOADKV(0, kcur, vcur);

  for (int kb = 0; kb <= kbmax; kb += 32){
    bf16_8 knxt[2][2], vnxt[4];
    if (kb < kbmax) LOADKV(kb + 32, knxt, vnxt);

    f32x4 s[2][4];
    #pragma unroll
    for (int kf = 0; kf < 2; kf++)
      #pragma unroll
      for (int qf = 0; qf < 4; qf++){
        f32x4 z = {0.f,0.f,0.f,0.f};
        z = __builtin_amdgcn_mfma_f32_16x16x32_bf16(kcur[kf][0], qfr[qf][0], z, 0, 0, 0);
        z = __builtin_amdgcn_mfma_f32_16x16x32_bf16(kcur[kf][1], qfr[qf][1], z, 0, 0, 0);
        s[kf][qf] = z;
      }

    if (kb + 31 > q0){
      #pragma unroll
      for (int kf = 0; kf < 2; kf++)
        #pragma unroll
        for (int qf = 0; qf < 4; qf++)
          #pragma unroll
          for (int j = 0; j < 4; j++)
            if (kb + kf*16 + g*4 + j > q0 + qf*16 + q15) s[kf][qf][j] = -1e30f;
    }

    #pragma unroll
    for (int qf = 0; qf < 4; qf++){
      float sm = -1e30f;
      #pragma unroll
      for (int kf = 0; kf < 2; kf++)
        #pragma unroll
        for (int j = 0; j < 4; j++) sm = fmaxf(sm, s[kf][qf][j]);
      sm = fmaxf(sm, __shfl_xor(sm, 16, 64));
      sm = fmaxf(sm, __shfl_xor(sm, 32, 64));
      float mn = fmaxf(mx[qf], sm);
      float c = __expf(mx[qf] - mn);
      mx[qf] = mn;
      float ps = 0.f;
      unsigned long long pw[2];
      #pragma unroll
      for (int kf = 0; kf < 2; kf++){
        unsigned long long w = 0;
        #pragma unroll
        for (int j = 0; j < 4; j++){
          float p = __expf(s[kf][qf][j] - mn);
          ps += p;
          w |= (unsigned long long)f2bf(p) << (16 * j);
        }
        pw[kf] = w;
      }
      ps += __shfl_xor(ps, 16, 64);
      ps += __shfl_xor(ps, 32, 64);
      lsum[qf] = lsum[qf] * c + ps;
      *(unsigned long long*)&plds[wave][qf*16 + q15][g*4]      = pw[0];
      *(unsigned long long*)&plds[wave][qf*16 + q15][16 + g*4] = pw[1];
      #pragma unroll
      for (int j = 0; j < 4; j++){
        float cr = __shfl(c, g*4 + j, 64);
        #pragma unroll
        for (int dc = 0; dc < 4; dc++) oacc[qf][dc][j] *= cr;
      }
    }

    asm volatile("s_waitcnt lgkmcnt(0)" ::: "memory");
    __builtin_amdgcn_sched_barrier(0);

    bf16_8 pa[4];
    #pragma unroll
    for (int qf = 0; qf < 4; qf++)
      pa[qf] = *(const bf16_8*)&plds[wave][qf*16 + q15][g*8];
    #pragma unroll
    for (int qf = 0; qf < 4; qf++)
      #pragma unroll
      for (int dc = 0; dc < 4; dc++)
        oacc[qf][dc] = __builtin_amdgcn_mfma_f32_16x16x32_bf16(pa[qf], vcur[dc], oacc[qf][dc], 0, 0, 0);

    if (kb < kbmax){
      #pragma unroll
      for (int kf = 0; kf < 2; kf++)
        #pragma unroll
        for (int kc = 0; kc < 2; kc++) kcur[kf][kc] = knxt[kf][kc];
      #pragma unroll
      for (int dc = 0; dc < 4; dc++) vcur[dc] = vnxt[dc];
    }
  }
#undef LOADKV

  u16* cb = ctx + ((size_t)(b * TSEQ + q0)) * EMB + h * 64;
  #pragma unroll
  for (int qf = 0; qf < 4; qf++){
    float inv = 1.f / lsum[qf];
    #pragma unroll
    for (int j = 0; j < 4; j++){
      float ir = __shfl(inv, g*4 + j, 64);
      int row = qf*16 + g*4 + j;
      #pragma unroll
      for (int dc = 0; dc < 4; dc++)
        cb[(size_t)row * EMB + dc*16 + q15] = f2bf(oacc[qf][dc][j] * ir);
    }
  }
}

// ---------------- final logits: out[b][v] = dot(last[b], tok[v]); one wave per v
__global__ __launch_bounds__(256) void logits_kernel(const float* __restrict__ last,
    const float* __restrict__ tok, float* __restrict__ out){
  __shared__ float ls[BBATCH * EMB];
  for (int i = threadIdx.x; i < BBATCH * EMB; i += 256) ls[i] = last[i];
  __syncthreads();
  int wave = threadIdx.x >> 6, lane = threadIdx.x & 63;
  int v = blockIdx.x * 4 + wave;
  if (v >= VOCAB) return;
  const float* tp = tok + (size_t)v * EMB;
  float acc[BBATCH];
  #pragma unroll
  for (int b = 0; b < BBATCH; b++) acc[b] = 0.f;
  #pragma unroll
  for (int i = 0; i < EMB/64; i++){
    float tv = tp[i*64 + lane];
    #pragma unroll
    for (int b = 0; b < BBATCH; b++) acc[b] += tv * ls[b*EMB + i*64 + lane];
  }
  #pragma unroll
  for (int b = 0; b < BBATCH; b++){
    float r = wred(acc[b]);
    if (lane == 0) out[(size_t)b * VOCAB + v] = r;
  }
}

extern "C" void kernel_launch(void* const* d_in, const int* in_sizes, int n_in,
                              void* d_out, int out_size, void* d_ws, size_t ws_size,
                              hipStream_t stream){
  const int*   x    = (const int*)  d_in[0];
  const float* tok  = (const float*)d_in[1];
  const float* pos  = (const float*)d_in[2];
  const float* ln1g = (const float*)d_in[3];
  const float* ln1b = (const float*)d_in[4];
  const float* Wqkv = (const float*)d_in[5];
  const float* bqkv = (const float*)d_in[6];
  const float* Wo   = (const float*)d_in[7];
  const float* bo   = (const float*)d_in[8];
  const float* ln2g = (const float*)d_in[9];
  const float* ln2b = (const float*)d_in[10];
  const float* W1   = (const float*)d_in[11];
  const float* b1   = (const float*)d_in[12];
  const float* W2   = (const float*)d_in[13];
  const float* b2   = (const float*)d_in[14];
  const float* lnfg = (const float*)d_in[15];
  const float* lnfb = (const float*)d_in[16];

  char* p = (char*)d_ws;
  u16* wqkvT = (u16*)p;  p += (size_t)LNUM*2304*768*2;
  u16* woT   = (u16*)p;  p += (size_t)LNUM*768*768*2;
  u16* w1T   = (u16*)p;  p += (size_t)LNUM*3072*768*2;
  u16* w2T   = (u16*)p;  p += (size_t)LNUM*768*3072*2;
  float* h   = (float*)p; p += (size_t)NTOK*EMB*4;
  u16* abuf  = (u16*)p;  p += (size_t)NTOK*EMB*2;      // ctx; also pf1 low half
  u16* vt    = (u16*)p;  p += (size_t)NTOK*EMB*2;      // V^T; also pf1 high half (contiguous with abuf)
  char* tmp  = p;        p += (size_t)NTOK*2304*4;     // 75.5MB overlay region
  float* lastb = (float*)p; p += (size_t)BBATCH*EMB*4;
  if (ws_size < (size_t)(p - (char*)d_ws)) return;

  const size_t SZ_A  = (size_t)NTOK*EMB*2;             // 12.6MB bf16 activations
  u16*   aln  = (u16*)tmp;                             // [0, 12.6)
  u16*   qkvb = (u16*)(tmp + SZ_A);                    // [12.6, 50.3)
  float* pp0  = (float*)(tmp + SZ_A);                  // proj partials [12.6, 62.9)
  float* pp1  = (float*)(tmp + SZ_A + (size_t)NTOK*EMB*4);
  u16*   a2   = (u16*)(tmp + SZ_A + 2*(size_t)NTOK*EMB*4);  // [62.9, 75.5)
  u16*   ff   = (u16*)tmp;                             // [0, 50.3)
  float* pf0  = (float*)(tmp + 4*SZ_A);                // [50.3, 75.5)
  float* pf1  = (float*)abuf;                          // abuf+vt contiguous [25.2MB]

  tcvt_kernel<<<dim3(2304/32, 768/32, LNUM), 256, 0, stream>>>(Wqkv, wqkvT, 768, 2304);
  tcvt_kernel<<<dim3(768/32,  768/32, LNUM), 256, 0, stream>>>(Wo,   woT,   768, 768);
  tcvt_kernel<<<dim3(3072/32, 768/32, LNUM), 256, 0, stream>>>(W1,   w1T,   768, 3072);
  tcvt_kernel<<<dim3(768/32, 3072/32, LNUM), 256, 0, stream>>>(W2,   w2T,   3072, 768);
  embed_kernel<<<NTOK, 256, 0, stream>>>(x, tok, pos, h);

  ln_kernel<<<NTOK, 256, 0, stream>>>(h, ln1g, ln1b, aln);
  for (int l = 0; l < LNUM; l++){
    // QKV: grid 64*9=576, GBN=3 (NBN=9)
    gemm_wt<4,3,1,3><<<(NTOK/128)*(2304/256), 256, 0, stream>>>(
        aln, wqkvT + (size_t)l*2304*768, bqkv + (size_t)l*2304, qkvb, nullptr, 768, 2304);
    vtrans_kernel<<<dim3(TSEQ/16, BBATCH*HNUM), 256, 0, stream>>>(qkvb, vt);
    attn_mfma<<<dim3(TSEQ/256, BBATCH*HNUM), 256, 0, stream>>>(qkvb, vt, abuf);
    // proj: split-K2, grid 64*6*2=768, GBN=3 (12 cols)
    gemm_wt<2,0,2,3><<<(NTOK/128)*(768/128)*2, 128, 0, stream>>>(
        abuf, woT + (size_t)l*768*768, nullptr, pp0, pp1, 768, 768);
    ln_merge<0><<<NTOK, 256, 0, stream>>>(h, pp0, pp1, bo + (size_t)l*768,
        ln2g + (size_t)l*EMB, ln2b + (size_t)l*EMB, h, a2);
    // FF1: grid 64*12=768, GBN=4 (NBN=12), gelu bf16
    gemm_wt<4,2,1,4><<<(NTOK/128)*(3072/256), 256, 0, stream>>>(
        a2, w1T + (size_t)l*3072*768, b1 + (size_t)l*3072, ff, nullptr, 768, 3072);
    // FF2: split-K2 (K=3072), grid 768, GBN=3 (12 cols)
    gemm_wt<2,0,2,3><<<(NTOK/128)*(768/128)*2, 128, 0, stream>>>(
        ff, w2T + (size_t)l*768*3072, nullptr, pf0, pf1, 3072, 768);
    if (l < LNUM - 1)
      ln_merge<0><<<NTOK, 256, 0, stream>>>(h, pf0, pf1, b2 + (size_t)l*768,
          ln1g + (size_t)(l+1)*EMB, ln1b + (size_t)(l+1)*EMB, h, aln);
  }
  ln_merge<1><<<BBATCH, 256, 0, stream>>>(h, pf0, pf1, b2 + (size_t)(LNUM-1)*768,
      lnfg, lnfb, nullptr, lastb);
  logits_kernel<<<(VOCAB + 3)/4, 256, 0, stream>>>(lastb, tok, (float*)d_out);
}